// Round 1
// baseline (344.854 us; speedup 1.0000x reference)
//
#include <hip/hip_runtime.h>
#include <math.h>

#define BATCH 8
#define NPTS  4096
#define CF    256
#define TOPK  16
#define TOTQ  (BATCH*NPTS)
#define EPOFF ((size_t)TOTQ*CF)

// ---------------------------------------------------------------------------
// prep: pack xyz rows into float4 (x,y,z,|p|^2) table in ws
// ---------------------------------------------------------------------------
__global__ __launch_bounds__(256) void prep_xyz_k(const float* __restrict__ xyz,
                                                  float4* __restrict__ tab) {
    int i = blockIdx.x*256 + threadIdx.x;
    if (i < TOTQ) {
        float x = xyz[3*i], y = xyz[3*i+1], z = xyz[3*i+2];
        tab[i] = make_float4(x, y, z, x*x + y*y + z*z);
    }
}

// ---------------------------------------------------------------------------
// kernel A: brute-force KNN (4 threads/query, LDS-buffered top-16) + geo
// features + geo MLP.  512 blocks x 256 threads; 64 queries/block.
// ---------------------------------------------------------------------------
__global__ __launch_bounds__(256, 2) void knn_geo_k(
    const float4* __restrict__ tab,
    const float* __restrict__ g_w1, const float* __restrict__ g_b1,
    const float* __restrict__ g_lnw, const float* __restrict__ g_lnb,
    const float* __restrict__ g_w2, const float* __restrict__ g_b2,
    float* __restrict__ geo_out)
{
    __shared__ float2 lst[TOPK][256];        // scan buffers, then sorted lists
    __shared__ float4 coords[64][TOPK+1];    // +1 f4 pad vs bank conflicts
    __shared__ float s_w1[320], s_b1[32], s_lnw[32], s_lnb[32], s_w2[512], s_b2[16];

    const int tid = threadIdx.x;
    for (int v = tid; v < 320; v += 256) s_w1[v] = g_w1[v];
    for (int v = tid; v < 512; v += 256) s_w2[v] = g_w2[v];
    if (tid < 32) { s_b1[tid] = g_b1[tid]; s_lnw[tid] = g_lnw[tid]; s_lnb[tid] = g_lnb[tid]; }
    if (tid < 16) s_b2[tid] = g_b2[tid];

    const int ql = tid & 63;                 // query within block (lanes = queries)
    const int qg = blockIdx.x*64 + ql;       // global query id
    const int b  = blockIdx.x >> 6;          // 64 blocks per batch
    const float4* __restrict__ ctab = tab + b*NPTS;
    // quarter id is wave-uniform -> force scalar so candidate loads go s_load
    const int ibase = __builtin_amdgcn_readfirstlane((tid >> 6) << 10);

    float4 q4 = tab[qg];
    const float qx = q4.x, qy = q4.y, qz = q4.z, qs = q4.w;

    float vals[TOPK]; int idxs[TOPK];
    #pragma unroll
    for (int j = 0; j < TOPK; ++j) { vals[j] = -INFINITY; idxs[j] = 0; }
    int   cnt = 0;
    float thr = -INFINITY;

    auto flushbuf = [&]() {
        for (int e = 0; e < cnt; ++e) {      // per-lane trip count, lanes flush in parallel
            float2 en = lst[e][tid];
            float pv = en.x;
            int   pj = __float_as_int(en.y);
            if (pv > vals[TOPK-1]) {
                #pragma unroll
                for (int j = TOPK-1; j >= 1; --j) {
                    bool shift = pv > vals[j-1];
                    bool place = (!shift) && (pv > vals[j]);
                    vals[j] = shift ? vals[j-1] : (place ? pv : vals[j]);
                    idxs[j] = shift ? idxs[j-1] : (place ? pj : idxs[j]);
                }
                if (pv > vals[0]) { vals[0] = pv; idxs[0] = pj; }
            }
        }
    };

    // scan 1024 candidates, double-buffered batches of 8 (uniform -> scalar loads)
    float4 cbuf[8];
    #pragma unroll
    for (int u = 0; u < 8; ++u) cbuf[u] = ctab[ibase + u];

    for (int ib = 0; ib < 1024; ib += 8) {
        float4 cur[8];
        #pragma unroll
        for (int u = 0; u < 8; ++u) cur[u] = cbuf[u];
        if (ib + 8 < 1024) {
            #pragma unroll
            for (int u = 0; u < 8; ++u) cbuf[u] = ctab[ibase + ib + 8 + u];
        }
        #pragma unroll
        for (int u = 0; u < 8; ++u) {
            float dot = fmaf(qx, cur[u].x, fmaf(qy, cur[u].y, qz*cur[u].z));
            float pd  = fmaf(2.f, dot, -(qs + cur[u].w));
            if (pd > thr) {                       // strict > : jax top_k tie rule
                lst[cnt][tid] = make_float2(pd, __int_as_float(ibase + ib + u));
                ++cnt;
            }
        }
        if (__any(cnt > 8)) { flushbuf(); cnt = 0; thr = vals[TOPK-1]; }
    }
    flushbuf();

    // publish sorted quarter-lists (transposed layout)
    #pragma unroll
    for (int e = 0; e < TOPK; ++e)
        lst[e][tid] = make_float2(vals[e], __int_as_float(idxs[e]));
    __syncthreads();

    // wave 0: 4-way merge + geometry features + geo MLP
    if (tid < 64) {
        const int q = tid;
        int p0 = 0, p1 = 0, p2 = 0, p3 = 0;
        float sx = 0, sy = 0, sz = 0;
        for (int r = 0; r < TOPK; ++r) {
            float2 h0 = lst[p0][q];
            float2 h1 = lst[p1][64 + q];
            float2 h2 = lst[p2][128 + q];
            float2 h3 = lst[p3][192 + q];
            float best = h0.x; int bj = __float_as_int(h0.y); int bs = 0;
            if (h1.x > best) { best = h1.x; bj = __float_as_int(h1.y); bs = 1; }
            if (h2.x > best) { best = h2.x; bj = __float_as_int(h2.y); bs = 2; }
            if (h3.x > best) { best = h3.x; bj = __float_as_int(h3.y); bs = 3; }
            p0 += (bs == 0); p1 += (bs == 1); p2 += (bs == 2); p3 += (bs == 3);
            float4 nb = ctab[bj];
            coords[q][r] = nb;
            sx += nb.x; sy += nb.y; sz += nb.z;
        }
        const float mx = sx/16.f, my = sy/16.f, mz = sz/16.f;
        float sxx = 0, syy = 0, szz = 0, sd = 0;
        float dist[TOPK];
        #pragma unroll
        for (int r = 0; r < TOPK; ++r) {
            float4 nb = coords[q][r];
            float cx = nb.x - mx, cy = nb.y - my, cz = nb.z - mz;
            sxx += cx*cx; syy += cy*cy; szz += cz*cz;
            float dd = sqrtf(cx*cx + cy*cy + cz*cz);
            dist[r] = dd; sd += dd;
        }
        const float md = sd/16.f;
        float sdd = 0;
        #pragma unroll
        for (int r = 0; r < TOPK; ++r) { float t = dist[r] - md; sdd += t*t; }
        const float c00 = sxx/16.f, c11 = syy/16.f, c22 = szz/16.f;
        const float trace = c00 + c11 + c22;
        const float det = fmaxf(c00*c11*c22, 1e-8f);
        const float s0 = sqrtf(sxx/15.f), s1 = sqrtf(syy/15.f), s2 = sqrtf(szz/15.f);
        const float stdd = sqrtf(sdd/15.f);
        const float tt = trace + 1e-6f;
        float geo[10] = {trace, det, s0, s1, s2, md, stdd, s0/tt, s1/tt, s2/tt};

        // geo_mlp: 10->32, LN, relu, 32->16
        float z1[32];
        #pragma unroll
        for (int jj = 0; jj < 32; ++jj) {
            float a = s_b1[jj];
            #pragma unroll
            for (int i = 0; i < 10; ++i) a = fmaf(geo[i], s_w1[i*32 + jj], a);
            z1[jj] = a;
        }
        float mzn = 0;
        #pragma unroll
        for (int jj = 0; jj < 32; ++jj) mzn += z1[jj];
        mzn /= 32.f;
        float vz = 0;
        #pragma unroll
        for (int jj = 0; jj < 32; ++jj) { float t = z1[jj] - mzn; vz += t*t; }
        vz /= 32.f;
        const float rs = 1.f/sqrtf(vz + 1e-5f);
        float h[32];
        #pragma unroll
        for (int jj = 0; jj < 32; ++jj)
            h[jj] = fmaxf((z1[jj]-mzn)*rs*s_lnw[jj] + s_lnb[jj], 0.f);
        float og[16];
        #pragma unroll
        for (int c = 0; c < 16; ++c) {
            float a = s_b2[c];
            #pragma unroll
            for (int i = 0; i < 32; ++i) a = fmaf(h[i], s_w2[i*16 + c], a);
            og[c] = a;
        }
        float4* gout = (float4*)(geo_out + (size_t)qg*16);
        gout[0] = make_float4(og[0],  og[1],  og[2],  og[3]);
        gout[1] = make_float4(og[4],  og[5],  og[6],  og[7]);
        gout[2] = make_float4(og[8],  og[9],  og[10], og[11]);
        gout[3] = make_float4(og[12], og[13], og[14], og[15]);
    }
}

// ---------------------------------------------------------------------------
// kernel B: edge_pred (272->64 LN relu ->1 sigmoid) + edge_refine
// (256x256 GEMM + LN256 + relu) + residual.  1024 blocks, 32 points/block.
// ---------------------------------------------------------------------------
__global__ __launch_bounds__(256, 2) void edge_k(
    const float* __restrict__ feat, const float* __restrict__ geo16,
    const float* __restrict__ e_w1, const float* __restrict__ e_b1,
    const float* __restrict__ e_lnw, const float* __restrict__ e_lnb,
    const float* __restrict__ e_w2, const float* __restrict__ e_b2,
    const float* __restrict__ r_w,  const float* __restrict__ r_b,
    const float* __restrict__ r_lnw, const float* __restrict__ r_lnb,
    float* __restrict__ out)
{
    __shared__ float fl[32*260];   // feature tile, padded stride
    __shared__ float wb[4096];     // weight chunk buffer (16KB)
    __shared__ float gl[512];      // geo tile 32x16

    const int tid = threadIdx.x;
    const int pbase = blockIdx.x*32;

    {   // stage features + geo
        const float4* f4 = (const float4*)(feat + (size_t)pbase*CF);
        #pragma unroll
        for (int k = 0; k < 8; ++k) {
            int v = tid + k*256;
            float4 x = f4[v];
            *(float4*)&fl[(v >> 6)*260 + (v & 63)*4] = x;
        }
        if (tid < 128) {
            float4 x = ((const float4*)(geo16 + (size_t)pbase*16))[tid];
            *(float4*)&gl[(tid >> 2)*16 + (tid & 3)*4] = x;
        }
    }
    __syncthreads();

    const int pq = tid >> 4, cq = tid & 15;
    const int p0 = pq*2, p1 = p0 + 1;

    // ---- phase 2: h1 = comb @ e_w1 (+b), LN64, relu, dot e_w2, sigmoid ----
    float a0[4] = {0,0,0,0}, a1[4] = {0,0,0,0};
    for (int kc = 0; kc < 256; kc += 64) {
        __syncthreads();
        #pragma unroll
        for (int k = 0; k < 4; ++k) {
            int v = tid + k*256;
            *(float4*)&wb[(v >> 4)*64 + (v & 15)*4] =
                *(const float4*)&e_w1[(size_t)(kc + (v >> 4))*64 + (v & 15)*4];
        }
        __syncthreads();
        #pragma unroll 8
        for (int k = 0; k < 64; ++k) {
            float f0 = fl[p0*260 + kc + k];
            float f1 = fl[p1*260 + kc + k];
            float4 w = *(float4*)&wb[k*64 + cq*4];
            a0[0] = fmaf(f0, w.x, a0[0]); a0[1] = fmaf(f0, w.y, a0[1]);
            a0[2] = fmaf(f0, w.z, a0[2]); a0[3] = fmaf(f0, w.w, a0[3]);
            a1[0] = fmaf(f1, w.x, a1[0]); a1[1] = fmaf(f1, w.y, a1[1]);
            a1[2] = fmaf(f1, w.z, a1[2]); a1[3] = fmaf(f1, w.w, a1[3]);
        }
    }
    __syncthreads();
    {   // geo rows 256..271 of e_w1
        int v = tid;
        *(float4*)&wb[(v >> 4)*64 + (v & 15)*4] =
            *(const float4*)&e_w1[(size_t)(256 + (v >> 4))*64 + (v & 15)*4];
    }
    __syncthreads();
    #pragma unroll
    for (int k = 0; k < 16; ++k) {
        float f0 = gl[p0*16 + k];
        float f1 = gl[p1*16 + k];
        float4 w = *(float4*)&wb[k*64 + cq*4];
        a0[0] = fmaf(f0, w.x, a0[0]); a0[1] = fmaf(f0, w.y, a0[1]);
        a0[2] = fmaf(f0, w.z, a0[2]); a0[3] = fmaf(f0, w.w, a0[3]);
        a1[0] = fmaf(f1, w.x, a1[0]); a1[1] = fmaf(f1, w.y, a1[1]);
        a1[2] = fmaf(f1, w.z, a1[2]); a1[3] = fmaf(f1, w.w, a1[3]);
    }
    {
        float4 bb = *(const float4*)&e_b1[cq*4];
        a0[0]+=bb.x; a0[1]+=bb.y; a0[2]+=bb.z; a0[3]+=bb.w;
        a1[0]+=bb.x; a1[1]+=bb.y; a1[2]+=bb.z; a1[3]+=bb.w;
    }
    float s0 = a0[0]+a0[1]+a0[2]+a0[3];
    float s1 = a1[0]+a1[1]+a1[2]+a1[3];
    #pragma unroll
    for (int sw = 1; sw < 16; sw <<= 1) { s0 += __shfl_xor(s0, sw); s1 += __shfl_xor(s1, sw); }
    const float m0 = s0/64.f, m1 = s1/64.f;
    float v0 = 0, v1 = 0;
    #pragma unroll
    for (int j = 0; j < 4; ++j) { float t0 = a0[j]-m0, t1 = a1[j]-m1; v0 += t0*t0; v1 += t1*t1; }
    #pragma unroll
    for (int sw = 1; sw < 16; sw <<= 1) { v0 += __shfl_xor(v0, sw); v1 += __shfl_xor(v1, sw); }
    const float r0 = 1.f/sqrtf(v0/64.f + 1e-5f);
    const float r1 = 1.f/sqrtf(v1/64.f + 1e-5f);
    float4 lw = *(const float4*)&e_lnw[cq*4];
    float4 lb = *(const float4*)&e_lnb[cq*4];
    float4 w2 = *(const float4*)&e_w2[cq*4];
    float d0 = 0, d1 = 0;
    {
        float hh;
        hh = fmaxf((a0[0]-m0)*r0*lw.x + lb.x, 0.f); d0 = fmaf(hh, w2.x, d0);
        hh = fmaxf((a0[1]-m0)*r0*lw.y + lb.y, 0.f); d0 = fmaf(hh, w2.y, d0);
        hh = fmaxf((a0[2]-m0)*r0*lw.z + lb.z, 0.f); d0 = fmaf(hh, w2.z, d0);
        hh = fmaxf((a0[3]-m0)*r0*lw.w + lb.w, 0.f); d0 = fmaf(hh, w2.w, d0);
        hh = fmaxf((a1[0]-m1)*r1*lw.x + lb.x, 0.f); d1 = fmaf(hh, w2.x, d1);
        hh = fmaxf((a1[1]-m1)*r1*lw.y + lb.y, 0.f); d1 = fmaf(hh, w2.y, d1);
        hh = fmaxf((a1[2]-m1)*r1*lw.z + lb.z, 0.f); d1 = fmaf(hh, w2.z, d1);
        hh = fmaxf((a1[3]-m1)*r1*lw.w + lb.w, 0.f); d1 = fmaf(hh, w2.w, d1);
    }
    #pragma unroll
    for (int sw = 1; sw < 16; sw <<= 1) { d0 += __shfl_xor(d0, sw); d1 += __shfl_xor(d1, sw); }
    const float eb2 = e_b2[0];
    const float ep0 = 1.f/(1.f + expf(-(d0 + eb2)));
    const float ep1 = 1.f/(1.f + expf(-(d1 + eb2)));
    if (cq == 0) {
        out[EPOFF + pbase + p0] = ep0;
        out[EPOFF + pbase + p1] = ep1;
    }

    // ---- phase 3: r = feat @ r_w (+b), LN256, relu, residual ----
    float b0[4][4], b1v[4][4];
    #pragma unroll
    for (int o = 0; o < 4; ++o)
        #pragma unroll
        for (int j = 0; j < 4; ++j) { b0[o][j] = 0.f; b1v[o][j] = 0.f; }

    for (int kc = 0; kc < 256; kc += 16) {
        __syncthreads();
        #pragma unroll
        for (int k = 0; k < 8; ++k) {
            int v = tid + k*256;
            *(float4*)&wb[(v >> 6)*256 + (v & 63)*4] =
                *(const float4*)&r_w[(size_t)(kc + (v >> 6))*256 + (v & 63)*4];
        }
        __syncthreads();
        #pragma unroll
        for (int k = 0; k < 16; ++k) {
            float f0 = fl[p0*260 + kc + k];
            float f1 = fl[p1*260 + kc + k];
            #pragma unroll
            for (int o = 0; o < 4; ++o) {
                float4 w = *(float4*)&wb[k*256 + o*64 + cq*4];
                b0[o][0] = fmaf(f0, w.x, b0[o][0]); b0[o][1] = fmaf(f0, w.y, b0[o][1]);
                b0[o][2] = fmaf(f0, w.z, b0[o][2]); b0[o][3] = fmaf(f0, w.w, b0[o][3]);
                b1v[o][0] = fmaf(f1, w.x, b1v[o][0]); b1v[o][1] = fmaf(f1, w.y, b1v[o][1]);
                b1v[o][2] = fmaf(f1, w.z, b1v[o][2]); b1v[o][3] = fmaf(f1, w.w, b1v[o][3]);
            }
        }
    }
    #pragma unroll
    for (int o = 0; o < 4; ++o) {
        float4 rb = *(const float4*)&r_b[o*64 + cq*4];
        b0[o][0]+=rb.x; b0[o][1]+=rb.y; b0[o][2]+=rb.z; b0[o][3]+=rb.w;
        b1v[o][0]+=rb.x; b1v[o][1]+=rb.y; b1v[o][2]+=rb.z; b1v[o][3]+=rb.w;
    }
    float S0 = 0, S1 = 0;
    #pragma unroll
    for (int o = 0; o < 4; ++o)
        #pragma unroll
        for (int j = 0; j < 4; ++j) { S0 += b0[o][j]; S1 += b1v[o][j]; }
    #pragma unroll
    for (int sw = 1; sw < 16; sw <<= 1) { S0 += __shfl_xor(S0, sw); S1 += __shfl_xor(S1, sw); }
    const float M0 = S0/256.f, M1 = S1/256.f;
    float V0 = 0, V1 = 0;
    #pragma unroll
    for (int o = 0; o < 4; ++o)
        #pragma unroll
        for (int j = 0; j < 4; ++j) {
            float t0 = b0[o][j]-M0, t1 = b1v[o][j]-M1;
            V0 += t0*t0; V1 += t1*t1;
        }
    #pragma unroll
    for (int sw = 1; sw < 16; sw <<= 1) { V0 += __shfl_xor(V0, sw); V1 += __shfl_xor(V1, sw); }
    const float R0 = 1.f/sqrtf(V0/256.f + 1e-5f);
    const float R1 = 1.f/sqrtf(V1/256.f + 1e-5f);

    #pragma unroll
    for (int o = 0; o < 4; ++o) {
        float4 lw4 = *(const float4*)&r_lnw[o*64 + cq*4];
        float4 lb4 = *(const float4*)&r_lnb[o*64 + cq*4];
        float4 f0v = *(float4*)&fl[p0*260 + o*64 + cq*4];
        float4 f1v = *(float4*)&fl[p1*260 + o*64 + cq*4];
        float4 o0, o1;
        o0.x = f0v.x + fmaxf((b0[o][0]-M0)*R0*lw4.x + lb4.x, 0.f)*ep0;
        o0.y = f0v.y + fmaxf((b0[o][1]-M0)*R0*lw4.y + lb4.y, 0.f)*ep0;
        o0.z = f0v.z + fmaxf((b0[o][2]-M0)*R0*lw4.z + lb4.z, 0.f)*ep0;
        o0.w = f0v.w + fmaxf((b0[o][3]-M0)*R0*lw4.w + lb4.w, 0.f)*ep0;
        o1.x = f1v.x + fmaxf((b1v[o][0]-M1)*R1*lw4.x + lb4.x, 0.f)*ep1;
        o1.y = f1v.y + fmaxf((b1v[o][1]-M1)*R1*lw4.y + lb4.y, 0.f)*ep1;
        o1.z = f1v.z + fmaxf((b1v[o][2]-M1)*R1*lw4.z + lb4.z, 0.f)*ep1;
        o1.w = f1v.w + fmaxf((b1v[o][3]-M1)*R1*lw4.w + lb4.w, 0.f)*ep1;
        *(float4*)&out[((size_t)(pbase + p0))*CF + o*64 + cq*4] = o0;
        *(float4*)&out[((size_t)(pbase + p1))*CF + o*64 + cq*4] = o1;
    }
}

// ---------------------------------------------------------------------------
extern "C" void kernel_launch(void* const* d_in, const int* in_sizes, int n_in,
                              void* d_out, int out_size, void* d_ws, size_t ws_size,
                              hipStream_t stream) {
    (void)in_sizes; (void)n_in; (void)out_size; (void)ws_size;
    const float* xyz   = (const float*)d_in[0];
    const float* feat  = (const float*)d_in[1];
    const float* g_w1  = (const float*)d_in[2];
    const float* g_b1  = (const float*)d_in[3];
    const float* g_lnw = (const float*)d_in[4];
    const float* g_lnb = (const float*)d_in[5];
    const float* g_w2  = (const float*)d_in[6];
    const float* g_b2  = (const float*)d_in[7];
    const float* e_w1  = (const float*)d_in[8];
    const float* e_b1  = (const float*)d_in[9];
    const float* e_lnw = (const float*)d_in[10];
    const float* e_lnb = (const float*)d_in[11];
    const float* e_w2  = (const float*)d_in[12];
    const float* e_b2  = (const float*)d_in[13];
    const float* r_w   = (const float*)d_in[14];
    const float* r_b   = (const float*)d_in[15];
    const float* r_lnw = (const float*)d_in[16];
    const float* r_lnb = (const float*)d_in[17];
    float* out = (float*)d_out;

    float*  geo_ws = (float*)d_ws;                                    // 2 MB
    float4* tab    = (float4*)((char*)d_ws + (size_t)TOTQ*16*sizeof(float)); // 512 KB

    hipLaunchKernelGGL(prep_xyz_k, dim3(TOTQ/256), dim3(256), 0, stream, xyz, tab);
    hipLaunchKernelGGL(knn_geo_k, dim3(TOTQ/64), dim3(256), 0, stream,
                       tab, g_w1, g_b1, g_lnw, g_lnb, g_w2, g_b2, geo_ws);
    hipLaunchKernelGGL(edge_k, dim3(TOTQ/32), dim3(256), 0, stream,
                       feat, geo_ws, e_w1, e_b1, e_lnw, e_lnb, e_w2, e_b2,
                       r_w, r_b, r_lnw, r_lnb, out);
}

// Round 2
// 282.401 us; speedup vs baseline: 1.2211x; 1.2211x over previous
//
#include <hip/hip_runtime.h>
#include <math.h>

#define BATCH 8
#define NPTS  4096
#define CF    256
#define TOPK  16
#define TOTQ  (BATCH*NPTS)
#define EPOFF ((size_t)TOTQ*CF)

typedef __attribute__((ext_vector_type(8))) short bf16x8;
typedef __attribute__((ext_vector_type(4))) float f32x4;

__device__ __forceinline__ unsigned short f2bf(float x) {
    union { float f; unsigned u; } a; a.f = x;
    unsigned r = a.u + 0x7fffu + ((a.u >> 16) & 1u);   // RNE
    return (unsigned short)(r >> 16);
}
__device__ __forceinline__ float bf2f(unsigned short h) {
    union { float f; unsigned u; } a; a.u = ((unsigned)h) << 16; return a.f;
}
__device__ __forceinline__ void gl_lds16(const void* g, void* l) {
    __builtin_amdgcn_global_load_lds(
        (const __attribute__((address_space(1))) unsigned int*)g,
        (__attribute__((address_space(3))) unsigned int*)l, 16, 0, 0);
}

// ---------------------------------------------------------------------------
// prep: pack xyz rows into float4 (x,y,z,|p|^2) table in ws
// ---------------------------------------------------------------------------
__global__ __launch_bounds__(256) void prep_xyz_k(const float* __restrict__ xyz,
                                                  float4* __restrict__ tab) {
    int i = blockIdx.x*256 + threadIdx.x;
    if (i < TOTQ) {
        float x = xyz[3*i], y = xyz[3*i+1], z = xyz[3*i+2];
        tab[i] = make_float4(x, y, z, x*x + y*y + z*z);
    }
}

// ---------------------------------------------------------------------------
// prep: split r_w / e_w1 into bf16 hi/lo MFMA-fragment-linear tables.
// Fragment layout per (kchunk c, ntile t): 512 bf16 at ((c*NT + t)<<9) +
// kg*128 + nn*8 + e  (kg = (k>>3)&3, e = k&7, nn = n&15) -> lane-linear 16B.
// e_w1 K padded 272->288 with zeros.
// ---------------------------------------------------------------------------
__global__ __launch_bounds__(256) void prep_w_k(
    const float* __restrict__ rw, const float* __restrict__ ew1,
    unsigned short* __restrict__ rwh, unsigned short* __restrict__ rwl,
    unsigned short* __restrict__ ewh, unsigned short* __restrict__ ewl)
{
    int t = blockIdx.x*256 + threadIdx.x;
    if (t < 65536) {                       // r_w [256][256]
        int k = t >> 8, n = t & 255;
        float x = rw[t];
        unsigned short h = f2bf(x);
        unsigned short l = f2bf(x - bf2f(h));
        int dst = (((k>>5)*16 + (n>>4)) << 9) + ((k>>3)&3)*128 + (n&15)*8 + (k&7);
        rwh[dst] = h; rwl[dst] = l;
    }
    if (t < 288*64) {                      // e_w1 [288][64] (zero-padded K)
        int k = t >> 6, n = t & 63;
        float x = (k < 272) ? ew1[k*64 + n] : 0.f;
        unsigned short h = f2bf(x);
        unsigned short l = f2bf(x - bf2f(h));
        int dst = (((k>>5)*4 + (n>>4)) << 9) + ((k>>3)&3)*128 + (n&15)*8 + (k&7);
        ewh[dst] = h; ewl[dst] = l;
    }
}

// ---------------------------------------------------------------------------
// kernel A: brute-force KNN + geo features + geo MLP (unchanged from R1)
// ---------------------------------------------------------------------------
__global__ __launch_bounds__(256, 2) void knn_geo_k(
    const float4* __restrict__ tab,
    const float* __restrict__ g_w1, const float* __restrict__ g_b1,
    const float* __restrict__ g_lnw, const float* __restrict__ g_lnb,
    const float* __restrict__ g_w2, const float* __restrict__ g_b2,
    float* __restrict__ geo_out)
{
    __shared__ float2 lst[TOPK][256];
    __shared__ float4 coords[64][TOPK+1];
    __shared__ float s_w1[320], s_b1[32], s_lnw[32], s_lnb[32], s_w2[512], s_b2[16];

    const int tid = threadIdx.x;
    for (int v = tid; v < 320; v += 256) s_w1[v] = g_w1[v];
    for (int v = tid; v < 512; v += 256) s_w2[v] = g_w2[v];
    if (tid < 32) { s_b1[tid] = g_b1[tid]; s_lnw[tid] = g_lnw[tid]; s_lnb[tid] = g_lnb[tid]; }
    if (tid < 16) s_b2[tid] = g_b2[tid];

    const int ql = tid & 63;
    const int qg = blockIdx.x*64 + ql;
    const int b  = blockIdx.x >> 6;
    const float4* __restrict__ ctab = tab + b*NPTS;
    const int ibase = __builtin_amdgcn_readfirstlane((tid >> 6) << 10);

    float4 q4 = tab[qg];
    const float qx = q4.x, qy = q4.y, qz = q4.z, qs = q4.w;

    float vals[TOPK]; int idxs[TOPK];
    #pragma unroll
    for (int j = 0; j < TOPK; ++j) { vals[j] = -INFINITY; idxs[j] = 0; }
    int   cnt = 0;
    float thr = -INFINITY;

    auto flushbuf = [&]() {
        for (int e = 0; e < cnt; ++e) {
            float2 en = lst[e][tid];
            float pv = en.x;
            int   pj = __float_as_int(en.y);
            if (pv > vals[TOPK-1]) {
                #pragma unroll
                for (int j = TOPK-1; j >= 1; --j) {
                    bool shift = pv > vals[j-1];
                    bool place = (!shift) && (pv > vals[j]);
                    vals[j] = shift ? vals[j-1] : (place ? pv : vals[j]);
                    idxs[j] = shift ? idxs[j-1] : (place ? pj : idxs[j]);
                }
                if (pv > vals[0]) { vals[0] = pv; idxs[0] = pj; }
            }
        }
    };

    float4 cbuf[8];
    #pragma unroll
    for (int u = 0; u < 8; ++u) cbuf[u] = ctab[ibase + u];

    for (int ib = 0; ib < 1024; ib += 8) {
        float4 cur[8];
        #pragma unroll
        for (int u = 0; u < 8; ++u) cur[u] = cbuf[u];
        if (ib + 8 < 1024) {
            #pragma unroll
            for (int u = 0; u < 8; ++u) cbuf[u] = ctab[ibase + ib + 8 + u];
        }
        #pragma unroll
        for (int u = 0; u < 8; ++u) {
            float dot = fmaf(qx, cur[u].x, fmaf(qy, cur[u].y, qz*cur[u].z));
            float pd  = fmaf(2.f, dot, -(qs + cur[u].w));
            if (pd > thr) {
                lst[cnt][tid] = make_float2(pd, __int_as_float(ibase + ib + u));
                ++cnt;
            }
        }
        if (__any(cnt > 8)) { flushbuf(); cnt = 0; thr = vals[TOPK-1]; }
    }
    flushbuf();

    #pragma unroll
    for (int e = 0; e < TOPK; ++e)
        lst[e][tid] = make_float2(vals[e], __int_as_float(idxs[e]));
    __syncthreads();

    if (tid < 64) {
        const int q = tid;
        int p0 = 0, p1 = 0, p2 = 0, p3 = 0;
        float sx = 0, sy = 0, sz = 0;
        for (int r = 0; r < TOPK; ++r) {
            float2 h0 = lst[p0][q];
            float2 h1 = lst[p1][64 + q];
            float2 h2 = lst[p2][128 + q];
            float2 h3 = lst[p3][192 + q];
            float best = h0.x; int bj = __float_as_int(h0.y); int bs = 0;
            if (h1.x > best) { best = h1.x; bj = __float_as_int(h1.y); bs = 1; }
            if (h2.x > best) { best = h2.x; bj = __float_as_int(h2.y); bs = 2; }
            if (h3.x > best) { best = h3.x; bj = __float_as_int(h3.y); bs = 3; }
            p0 += (bs == 0); p1 += (bs == 1); p2 += (bs == 2); p3 += (bs == 3);
            float4 nb = ctab[bj];
            coords[q][r] = nb;
            sx += nb.x; sy += nb.y; sz += nb.z;
        }
        const float mx = sx/16.f, my = sy/16.f, mz = sz/16.f;
        float sxx = 0, syy = 0, szz = 0, sd = 0;
        float dist[TOPK];
        #pragma unroll
        for (int r = 0; r < TOPK; ++r) {
            float4 nb = coords[q][r];
            float cx = nb.x - mx, cy = nb.y - my, cz = nb.z - mz;
            sxx += cx*cx; syy += cy*cy; szz += cz*cz;
            float dd = sqrtf(cx*cx + cy*cy + cz*cz);
            dist[r] = dd; sd += dd;
        }
        const float md = sd/16.f;
        float sdd = 0;
        #pragma unroll
        for (int r = 0; r < TOPK; ++r) { float t = dist[r] - md; sdd += t*t; }
        const float c00 = sxx/16.f, c11 = syy/16.f, c22 = szz/16.f;
        const float trace = c00 + c11 + c22;
        const float det = fmaxf(c00*c11*c22, 1e-8f);
        const float s0 = sqrtf(sxx/15.f), s1 = sqrtf(syy/15.f), s2 = sqrtf(szz/15.f);
        const float stdd = sqrtf(sdd/15.f);
        const float tt = trace + 1e-6f;
        float geo[10] = {trace, det, s0, s1, s2, md, stdd, s0/tt, s1/tt, s2/tt};

        float z1[32];
        #pragma unroll
        for (int jj = 0; jj < 32; ++jj) {
            float a = s_b1[jj];
            #pragma unroll
            for (int i = 0; i < 10; ++i) a = fmaf(geo[i], s_w1[i*32 + jj], a);
            z1[jj] = a;
        }
        float mzn = 0;
        #pragma unroll
        for (int jj = 0; jj < 32; ++jj) mzn += z1[jj];
        mzn /= 32.f;
        float vz = 0;
        #pragma unroll
        for (int jj = 0; jj < 32; ++jj) { float t = z1[jj] - mzn; vz += t*t; }
        vz /= 32.f;
        const float rs = 1.f/sqrtf(vz + 1e-5f);
        float h[32];
        #pragma unroll
        for (int jj = 0; jj < 32; ++jj)
            h[jj] = fmaxf((z1[jj]-mzn)*rs*s_lnw[jj] + s_lnb[jj], 0.f);
        float og[16];
        #pragma unroll
        for (int c = 0; c < 16; ++c) {
            float a = s_b2[c];
            #pragma unroll
            for (int i = 0; i < 32; ++i) a = fmaf(h[i], s_w2[i*16 + c], a);
            og[c] = a;
        }
        float4* gout = (float4*)(geo_out + (size_t)qg*16);
        gout[0] = make_float4(og[0],  og[1],  og[2],  og[3]);
        gout[1] = make_float4(og[4],  og[5],  og[6],  og[7]);
        gout[2] = make_float4(og[8],  og[9],  og[10], og[11]);
        gout[3] = make_float4(og[12], og[13], og[14], og[15]);
    }
}

// ---------------------------------------------------------------------------
// kernel B: split-bf16 MFMA edge_pred + edge_refine.
// 512 blocks x 256 thr (4 waves). M-tile = 64 points.
// Phase2: wave w -> rows w*16..+15, all 64 cols. K=288 (padded), 9 chunks.
// Phase3: wave w -> all 64 rows, cols [64w,64w+64). K=256, 8 chunks.
// D = Ah*Bh + Ah*Bl + Al*Bh   (Al*Bl ~ 2^-18, dropped)
// ---------------------------------------------------------------------------
__global__ __launch_bounds__(256, 1) void edge_k(
    const float* __restrict__ feat, const float* __restrict__ geo16,
    const unsigned short* __restrict__ rwh, const unsigned short* __restrict__ rwl,
    const unsigned short* __restrict__ ewh, const unsigned short* __restrict__ ewl,
    const float* __restrict__ e_b1, const float* __restrict__ e_lnw,
    const float* __restrict__ e_lnb, const float* __restrict__ e_w2,
    const float* __restrict__ e_b2,
    const float* __restrict__ r_b, const float* __restrict__ r_lnw,
    const float* __restrict__ r_lnb,
    float* __restrict__ out)
{
    __shared__ unsigned short sAh[64*296];      // 37888 B  (cols 0..255 feat, 256..271 geo, 272..287 zero)
    __shared__ unsigned short sAl[64*296];      // 37888 B
    __shared__ unsigned char  sB[65536];        // phase3 dbuf [0,32K)+[32K,64K); phase2 dbuf at 32K+{0,8K}; later sOut f32[64][256]
    __shared__ float s_eb1[64], s_elnw[64], s_elnb[64], s_ew2[64];
    __shared__ float s_rb[256], s_rlnw[256], s_rlnb[256];
    __shared__ float s_ep[64], s_m[64], s_rs[64];
    __shared__ float sPx[256], sPq[256];

    const int tid  = threadIdx.x;
    const int lane = tid & 63;
    const int wv   = tid >> 6;
    const int lr   = lane & 15;     // frag row/col within 16
    const int lg   = lane >> 4;     // k-group / row-group
    const int pbase = blockIdx.x * 64;

    // ---- consts ----
    if (tid < 64) { s_eb1[tid]=e_b1[tid]; s_elnw[tid]=e_lnw[tid]; s_elnb[tid]=e_lnb[tid]; s_ew2[tid]=e_w2[tid]; }
    s_rb[tid]=r_b[tid]; s_rlnw[tid]=r_lnw[tid]; s_rlnb[tid]=r_lnb[tid];

    // ---- stage A: features -> bf16 hi/lo in sA ----
    const float4* f4 = (const float4*)(feat + (size_t)pbase*CF);
    #pragma unroll
    for (int it = 0; it < 16; ++it) {
        int v = tid + it*256;
        float4 x = f4[v];
        int row = v >> 6, c0 = (v & 63)*4;
        unsigned short h0=f2bf(x.x), h1=f2bf(x.y), h2=f2bf(x.z), h3=f2bf(x.w);
        unsigned short l0=f2bf(x.x-bf2f(h0)), l1=f2bf(x.y-bf2f(h1));
        unsigned short l2=f2bf(x.z-bf2f(h2)), l3=f2bf(x.w-bf2f(h3));
        *(ushort4*)&sAh[row*296 + c0] = make_ushort4(h0,h1,h2,h3);
        *(ushort4*)&sAl[row*296 + c0] = make_ushort4(l0,l1,l2,l3);
    }
    {   // geo cols 256..271 + zero pad 272..287
        const float4* g4 = (const float4*)(geo16 + (size_t)pbase*16);
        float4 x = g4[tid];
        int row = tid >> 2, c0 = 256 + (tid & 3)*4;
        unsigned short h0=f2bf(x.x), h1=f2bf(x.y), h2=f2bf(x.z), h3=f2bf(x.w);
        unsigned short l0=f2bf(x.x-bf2f(h0)), l1=f2bf(x.y-bf2f(h1));
        unsigned short l2=f2bf(x.z-bf2f(h2)), l3=f2bf(x.w-bf2f(h3));
        *(ushort4*)&sAh[row*296 + c0] = make_ushort4(h0,h1,h2,h3);
        *(ushort4*)&sAl[row*296 + c0] = make_ushort4(l0,l1,l2,l3);
        int zc = 272 + (tid & 3)*4;
        *(ushort4*)&sAh[row*296 + zc] = make_ushort4(0,0,0,0);
        *(ushort4*)&sAl[row*296 + zc] = make_ushort4(0,0,0,0);
    }

    // ---- staging helpers ----
    auto stage3 = [&](int c, int buf) {     // 32 KB chunk of r_w frags
        const char* sh = (const char*)rwh + c*16384;
        const char* sl = (const char*)rwl + c*16384;
        char* dh = (char*)sB + buf*32768;
        char* dl = dh + 16384;
        #pragma unroll
        for (int i = 0; i < 4; ++i) {
            gl_lds16(sh + i*4096 + wv*1024 + lane*16, dh + i*4096 + wv*1024);
            gl_lds16(sl + i*4096 + wv*1024 + lane*16, dl + i*4096 + wv*1024);
        }
    };
    auto stage2 = [&](int c, int buf) {     // 8 KB chunk of e_w1 frags
        const char* sh = (const char*)ewh + c*4096;
        const char* sl = (const char*)ewl + c*4096;
        char* d = (char*)sB + 32768 + buf*8192;
        gl_lds16(sh + wv*1024 + lane*16, d + wv*1024);
        gl_lds16(sl + wv*1024 + lane*16, d + 4096 + wv*1024);
    };

    stage2(0, 0);          // phase2 chunk0
    stage3(0, 0);          // phase3 chunk0 (hidden under phase2)
    __syncthreads();

    // ================= phase 2: comb @ e_w1 =================
    f32x4 acc2[4];
    #pragma unroll
    for (int i = 0; i < 4; ++i) acc2[i] = (f32x4){0.f,0.f,0.f,0.f};
    const int arow2 = (wv*16 + lr)*296;
    for (int c = 0; c < 9; ++c) {
        if (c < 8) stage2(c+1, (c+1)&1);
        bf16x8 ah = *(const bf16x8*)&sAh[arow2 + c*32 + lg*8];
        bf16x8 al = *(const bf16x8*)&sAl[arow2 + c*32 + lg*8];
        const unsigned short* bb = (const unsigned short*)(sB + 32768 + (c&1)*8192);
        #pragma unroll
        for (int nt = 0; nt < 4; ++nt) {
            bf16x8 bh = *(const bf16x8*)&bb[nt*512 + lane*8];
            bf16x8 bl = *(const bf16x8*)&bb[2048 + nt*512 + lane*8];
            acc2[nt] = __builtin_amdgcn_mfma_f32_16x16x32_bf16(al, bh, acc2[nt], 0,0,0);
            acc2[nt] = __builtin_amdgcn_mfma_f32_16x16x32_bf16(ah, bl, acc2[nt], 0,0,0);
            acc2[nt] = __builtin_amdgcn_mfma_f32_16x16x32_bf16(ah, bh, acc2[nt], 0,0,0);
        }
        __syncthreads();
    }

    // phase2 epilogue: bias, LN64, relu, dot e_w2, sigmoid
    {
        float px[4] = {0,0,0,0}, pq[4] = {0,0,0,0};
        #pragma unroll
        for (int nt = 0; nt < 4; ++nt) {
            float bv = s_eb1[nt*16 + lr];
            #pragma unroll
            for (int j = 0; j < 4; ++j) {
                acc2[nt][j] += bv;
                px[j] += acc2[nt][j];
                pq[j] += acc2[nt][j]*acc2[nt][j];
            }
        }
        #pragma unroll
        for (int sw = 1; sw < 16; sw <<= 1) {
            #pragma unroll
            for (int j = 0; j < 4; ++j) { px[j] += __shfl_xor(px[j], sw); pq[j] += __shfl_xor(pq[j], sw); }
        }
        float mj[4], rj[4], dd[4] = {0,0,0,0};
        #pragma unroll
        for (int j = 0; j < 4; ++j) {
            mj[j] = px[j]*(1.f/64.f);
            float var = pq[j]*(1.f/64.f) - mj[j]*mj[j];
            rj[j] = rsqrtf(var + 1e-5f);
        }
        #pragma unroll
        for (int nt = 0; nt < 4; ++nt) {
            int col = nt*16 + lr;
            float lw = s_elnw[col], lb = s_elnb[col], w2 = s_ew2[col];
            #pragma unroll
            for (int j = 0; j < 4; ++j) {
                float h = fmaxf((acc2[nt][j]-mj[j])*rj[j]*lw + lb, 0.f);
                dd[j] = fmaf(h, w2, dd[j]);
            }
        }
        #pragma unroll
        for (int sw = 1; sw < 16; sw <<= 1) {
            #pragma unroll
            for (int j = 0; j < 4; ++j) dd[j] += __shfl_xor(dd[j], sw);
        }
        float eb2v = e_b2[0];
        #pragma unroll
        for (int j = 0; j < 4; ++j) {
            if (lr == j) {
                int row = wv*16 + lg*4 + j;
                float ep = 1.f/(1.f + expf(-(dd[j] + eb2v)));
                s_ep[row] = ep;
                out[EPOFF + pbase + row] = ep;
            }
        }
    }

    // ================= phase 3: feat @ r_w =================
    f32x4 acc3[4][4];
    #pragma unroll
    for (int mt = 0; mt < 4; ++mt)
        #pragma unroll
        for (int nt = 0; nt < 4; ++nt) acc3[mt][nt] = (f32x4){0.f,0.f,0.f,0.f};

    for (int c = 0; c < 8; ++c) {
        if (c < 7) stage3(c+1, (c+1)&1);
        bf16x8 ah[4], al[4];
        #pragma unroll
        for (int mt = 0; mt < 4; ++mt) {
            ah[mt] = *(const bf16x8*)&sAh[(mt*16+lr)*296 + c*32 + lg*8];
            al[mt] = *(const bf16x8*)&sAl[(mt*16+lr)*296 + c*32 + lg*8];
        }
        const unsigned short* bb = (const unsigned short*)(sB + (c&1)*32768);
        #pragma unroll
        for (int ntl = 0; ntl < 4; ++ntl) {
            int nt = wv*4 + ntl;
            bf16x8 bh = *(const bf16x8*)&bb[nt*512 + lane*8];
            bf16x8 bl = *(const bf16x8*)&bb[8192 + nt*512 + lane*8];
            #pragma unroll
            for (int mt = 0; mt < 4; ++mt) {
                acc3[mt][ntl] = __builtin_amdgcn_mfma_f32_16x16x32_bf16(al[mt], bh, acc3[mt][ntl], 0,0,0);
                acc3[mt][ntl] = __builtin_amdgcn_mfma_f32_16x16x32_bf16(ah[mt], bl, acc3[mt][ntl], 0,0,0);
                acc3[mt][ntl] = __builtin_amdgcn_mfma_f32_16x16x32_bf16(ah[mt], bh, acc3[mt][ntl], 0,0,0);
            }
        }
        __syncthreads();
    }

    // phase3 epilogue: bias + cross-wave LN256
    float qx[4][4], qq[4][4];
    #pragma unroll
    for (int mt = 0; mt < 4; ++mt)
        #pragma unroll
        for (int j = 0; j < 4; ++j) { qx[mt][j] = 0.f; qq[mt][j] = 0.f; }
    #pragma unroll
    for (int ntl = 0; ntl < 4; ++ntl) {
        int col = (wv*4 + ntl)*16 + lr;
        float bv = s_rb[col];
        #pragma unroll
        for (int mt = 0; mt < 4; ++mt)
            #pragma unroll
            for (int j = 0; j < 4; ++j) {
                acc3[mt][ntl][j] += bv;
                float v = acc3[mt][ntl][j];
                qx[mt][j] += v; qq[mt][j] += v*v;
            }
    }
    #pragma unroll
    for (int sw = 1; sw < 16; sw <<= 1) {
        #pragma unroll
        for (int mt = 0; mt < 4; ++mt)
            #pragma unroll
            for (int j = 0; j < 4; ++j) { qx[mt][j] += __shfl_xor(qx[mt][j], sw); qq[mt][j] += __shfl_xor(qq[mt][j], sw); }
    }
    if (lr == 0) {
        #pragma unroll
        for (int mt = 0; mt < 4; ++mt)
            #pragma unroll
            for (int j = 0; j < 4; ++j) {
                int row = mt*16 + lg*4 + j;
                sPx[wv*64 + row] = qx[mt][j];
                sPq[wv*64 + row] = qq[mt][j];
            }
    }
    __syncthreads();
    if (tid < 64) {
        float Sx = sPx[tid] + sPx[64+tid] + sPx[128+tid] + sPx[192+tid];
        float Sq = sPq[tid] + sPq[64+tid] + sPq[128+tid] + sPq[192+tid];
        float m  = Sx*(1.f/256.f);
        float var = Sq*(1.f/256.f) - m*m;
        s_m[tid]  = m;
        s_rs[tid] = rsqrtf(var + 1e-5f);
    }
    __syncthreads();

    // h = relu(LN) -> sOut (sB reused as f32[64][256])
    {
        float* sOut = (float*)sB;
        float lwv[4], lbv[4]; int colv[4];
        #pragma unroll
        for (int ntl = 0; ntl < 4; ++ntl) {
            colv[ntl] = (wv*4 + ntl)*16 + lr;
            lwv[ntl] = s_rlnw[colv[ntl]];
            lbv[ntl] = s_rlnb[colv[ntl]];
        }
        #pragma unroll
        for (int mt = 0; mt < 4; ++mt) {
            #pragma unroll
            for (int j = 0; j < 4; ++j) {
                int row = mt*16 + lg*4 + j;
                float m = s_m[row], rs = s_rs[row];
                #pragma unroll
                for (int ntl = 0; ntl < 4; ++ntl) {
                    float h = fmaxf((acc3[mt][ntl][j]-m)*rs*lwv[ntl] + lbv[ntl], 0.f);
                    sOut[row*256 + colv[ntl]] = h;
                }
            }
        }
    }
    __syncthreads();

    // final: out = feat + h*ep  (coalesced float4 stores)
    {
        const float* sOut = (const float*)sB;
        #pragma unroll
        for (int it = 0; it < 16; ++it) {
            int v = tid + it*256;
            int row = v >> 6, c0 = (v & 63)*4;
            float4 h4 = *(const float4*)&sOut[row*256 + c0];
            ushort4 hh = *(const ushort4*)&sAh[row*296 + c0];
            ushort4 ll = *(const ushort4*)&sAl[row*296 + c0];
            float ep = s_ep[row];
            float4 o;
            o.x = bf2f(hh.x) + bf2f(ll.x) + h4.x*ep;
            o.y = bf2f(hh.y) + bf2f(ll.y) + h4.y*ep;
            o.z = bf2f(hh.z) + bf2f(ll.z) + h4.z*ep;
            o.w = bf2f(hh.w) + bf2f(ll.w) + h4.w*ep;
            *(float4*)&out[(size_t)(pbase+row)*CF + c0] = o;
        }
    }
}

// ---------------------------------------------------------------------------
extern "C" void kernel_launch(void* const* d_in, const int* in_sizes, int n_in,
                              void* d_out, int out_size, void* d_ws, size_t ws_size,
                              hipStream_t stream) {
    (void)in_sizes; (void)n_in; (void)out_size; (void)ws_size;
    const float* xyz   = (const float*)d_in[0];
    const float* feat  = (const float*)d_in[1];
    const float* g_w1  = (const float*)d_in[2];
    const float* g_b1  = (const float*)d_in[3];
    const float* g_lnw = (const float*)d_in[4];
    const float* g_lnb = (const float*)d_in[5];
    const float* g_w2  = (const float*)d_in[6];
    const float* g_b2  = (const float*)d_in[7];
    const float* e_w1  = (const float*)d_in[8];
    const float* e_b1  = (const float*)d_in[9];
    const float* e_lnw = (const float*)d_in[10];
    const float* e_lnb = (const float*)d_in[11];
    const float* e_w2  = (const float*)d_in[12];
    const float* e_b2  = (const float*)d_in[13];
    const float* r_w   = (const float*)d_in[14];
    const float* r_b   = (const float*)d_in[15];
    const float* r_lnw = (const float*)d_in[16];
    const float* r_lnb = (const float*)d_in[17];
    float* out = (float*)d_out;

    char* ws = (char*)d_ws;
    float*          geo_ws = (float*)ws;                       // 2 MB
    float4*         tab    = (float4*)(ws + 0x200000);         // 512 KB
    unsigned short* rwh    = (unsigned short*)(ws + 0x280000); // 128 KB
    unsigned short* rwl    = (unsigned short*)(ws + 0x2A0000); // 128 KB
    unsigned short* ewh    = (unsigned short*)(ws + 0x2C0000); // 36 KB (64 KB slot)
    unsigned short* ewl    = (unsigned short*)(ws + 0x2D0000); // 36 KB

    hipLaunchKernelGGL(prep_xyz_k, dim3(TOTQ/256), dim3(256), 0, stream, xyz, tab);
    hipLaunchKernelGGL(prep_w_k, dim3(256), dim3(256), 0, stream,
                       r_w, e_w1, rwh, rwl, ewh, ewl);
    hipLaunchKernelGGL(knn_geo_k, dim3(TOTQ/64), dim3(256), 0, stream,
                       tab, g_w1, g_b1, g_lnw, g_lnb, g_w2, g_b2, geo_ws);
    hipLaunchKernelGGL(edge_k, dim3(TOTQ/64), dim3(256), 0, stream,
                       feat, geo_ws, rwh, rwl, ewh, ewl,
                       e_b1, e_lnw, e_lnb, e_w2, e_b2,
                       r_b, r_lnw, r_lnb, out);
}